// Round 5
// baseline (5421.497 us; speedup 1.0000x reference)
//
#include <hip/hip_runtime.h>
#include <hip/hip_bf16.h>

#define SEQ    256
#define BATCH  64
#define HID    1024
#define G4     4096
#define NWG    256
#define GWG    64     // WGs per batch-group
#define GB     16     // batch rows per group

typedef __bf16 bf16x8 __attribute__((ext_vector_type(8)));
typedef float  f32x4  __attribute__((ext_vector_type(4)));
typedef unsigned short u16;

__device__ __forceinline__ u16 f2bf(float f) {
    unsigned int u = __float_as_uint(f);
    unsigned int r = (u + 0x7fffu + ((u >> 16) & 1u)) >> 16;  // RNE
    return (u16)r;
}
__device__ __forceinline__ float sigmoid_f(float x) {
    x = fminf(fmaxf(x, -30.f), 30.f);
    return 1.f / (1.f + __expf(-x));
}
__device__ __forceinline__ float tanh_f(float x) {
    x = fminf(fmaxf(x, -15.f), 15.f);
    float e2 = __expf(2.f * x);
    return (e2 - 1.f) / (e2 + 1.f);
}

// ---------------- prep: fp32->bf16 for x and Wx, zero flags ----------------
__global__ void prep_kernel(const float* __restrict__ x, u16* __restrict__ Xbf,
                            const float* __restrict__ Wx, u16* __restrict__ WxBf,
                            int* __restrict__ flags) {
    int idx = blockIdx.x * blockDim.x + threadIdx.x;
    if (idx < 1024) flags[idx] = 0;
    int stride = gridDim.x * blockDim.x;
    int nx4 = SEQ * BATCH * HID / 4;
    const float4* in4 = (const float4*)x;
    ushort4* out4 = (ushort4*)Xbf;
    for (int i = idx; i < nx4; i += stride) {
        float4 v = in4[i];
        ushort4 o; o.x = f2bf(v.x); o.y = f2bf(v.y); o.z = f2bf(v.z); o.w = f2bf(v.w);
        out4[i] = o;
    }
    int nw4 = 2 * G4 * HID / 4;
    const float4* w4 = (const float4*)Wx;
    ushort4* wo4 = (ushort4*)WxBf;
    for (int i = idx; i < nw4; i += stride) {
        float4 v = w4[i];
        ushort4 o; o.x = f2bf(v.x); o.y = f2bf(v.y); o.z = f2bf(v.z); o.w = f2bf(v.w);
        wo4[i] = o;
    }
}

// ---- group-local flag barrier: WG writes own flag, 64 lanes poll 64 flags ----
__device__ __forceinline__ void bar_signal(int* gflags, int wl, int fid) {
    asm volatile("s_waitcnt vmcnt(0)" ::: "memory");  // my sc-stores visible at L3
    __syncthreads();                                  // whole WG drained
    if (threadIdx.x == 0)
        __hip_atomic_store(gflags + wl, fid, __ATOMIC_RELAXED, __HIP_MEMORY_SCOPE_AGENT);
}
__device__ __forceinline__ void bar_poll(int* gflags, int fid) {
    if (threadIdx.x < 64) {
        while (__hip_atomic_load(gflags + (int)threadIdx.x, __ATOMIC_RELAXED,
                                 __HIP_MEMORY_SCOPE_AGENT) < fid) { }
    }
    __syncthreads();
}

// x-GEMM: A (x) and B (Wx bf16) streamed from global/L2; 32 MFMAs, serial chain OK (overlap window)
__device__ __forceinline__ f32x4 xgemm(const u16* __restrict__ A, const u16* __restrict__ B) {
    f32x4 acc = {0.f, 0.f, 0.f, 0.f};
    #pragma unroll 8
    for (int ks = 0; ks < 32; ++ks) {
        bf16x8 a = *(const bf16x8*)(A + ks * 32);
        bf16x8 b = *(const bf16x8*)(B + ks * 32);
        acc = __builtin_amdgcn_mfma_f32_16x16x32_bf16(a, b, acc, 0, 0, 0);
    }
    return acc;
}

#define LDH(var, OFFS) \
    asm volatile("global_load_dwordx4 %0, %1, off offset:" OFFS " sc0 sc1" \
                 : "=v"(var) : "v"(hsrc))

// ---------------- persistent cooperative LSTM, 4 independent batch-groups ----------------
// WG wg: group g = wg>>6 (16 batch rows), slice wl = wg&63 -> h-cols [16wl,16wl+16).
// Wave wv = gate type (i,f,g,o): gate rows wv*1024 + hc0 + [0,16).
__global__ void __launch_bounds__(256, 1) lstm_coop(
    const u16* __restrict__ Xbf,   // [SEQ][BATCH][HID] bf16
    u16* __restrict__ Y0bf,        // [SEQ][BATCH][HID] bf16 (layer-0 h, sc-accessed)
    const u16* __restrict__ WxBf,  // [2][4096][1024] bf16
    u16* __restrict__ hbuf,        // [4 groups][2][GB][HID] bf16 (sc-accessed)
    int* __restrict__ flags,       // [4][64]
    const float* __restrict__ h0,
    const float* __restrict__ c0,
    const float* __restrict__ Wh,  // [2][4096][1024] fp32
    const float* __restrict__ bx,
    const float* __restrict__ bh,
    float* __restrict__ out)       // ys | hT | cT
{
    __shared__ u16 WhL[4][16384];  // per-wave tile, fragment order: [(ks*64+lane)*8]
    __shared__ u16 hstage[16384];  // group h, fragment order; gbuf aliased inside

    const int wg   = blockIdx.x;
    const int g    = wg >> 6;
    const int wl   = wg & 63;
    const int hc0  = wl * 16;
    const int tid  = threadIdx.x;
    const int wv   = tid >> 6;       // gate type
    const int lane = tid & 63;
    const int fr   = lane & 15;      // frag row (A batch-row / B gate-col / D col)
    const int fg   = lane >> 4;      // k-group
    const int b_l  = tid >> 4;       // cell phase: batch-local 0..15
    const int c_l  = tid & 15;       // cell phase: col-local 0..15
    // h-stage phase mapping
    const int sr   = tid >> 4;       // batch row 0..15
    const int scb  = tid & 15;       // col block

    float* gbuf = (float*)hstage;    // [4][16][17] fp32, 4352B, aliased (lifetime-safe)

    int fid = 0;
    int* gflags = flags + g * 64;

    float* ys = out;
    float* hT = out + (size_t)SEQ * BATCH * HID;
    float* cT = hT + (size_t)2 * BATCH * HID;

    for (int layer = 0; layer < 2; ++layer) {
        // ---- stage Wh tile into LDS, fragment order, fp32->bf16 ----
        {
            size_t rowg = (size_t)layer * G4 + (size_t)wv * 1024 + hc0 + fr;
            const float* src = Wh + rowg * HID + fg * 8;
            u16* dst = &WhL[wv][lane * 8];
            #pragma unroll 4
            for (int ks = 0; ks < 32; ++ks) {
                float4 w0 = *(const float4*)(src + ks * 32);
                float4 w1 = *(const float4*)(src + ks * 32 + 4);
                ushort4 o0, o1;
                o0.x = f2bf(w0.x); o0.y = f2bf(w0.y); o0.z = f2bf(w0.z); o0.w = f2bf(w0.w);
                o1.x = f2bf(w1.x); o1.y = f2bf(w1.y); o1.z = f2bf(w1.z); o1.w = f2bf(w1.w);
                *(ushort4*)(dst + ks * 512)     = o0;
                *(ushort4*)(dst + ks * 512 + 4) = o1;
            }
        }
        const float bias_v = bx[layer * G4 + wv * 1024 + hc0 + fr]
                           + bh[layer * G4 + wv * 1024 + hc0 + fr];

        // ---- init h (sc-stores, buffer 0) and per-thread c ----
        {
            float hv = h0[(size_t)layer * BATCH * HID + (size_t)(g * GB + b_l) * HID + hc0 + c_l];
            u16* hdst = hbuf + ((size_t)(g * 2 + 0) * GB + b_l) * HID + hc0 + c_l;
            unsigned int hv32 = f2bf(hv);
            asm volatile("global_store_short %0, %1, off sc0 sc1" :: "v"(hdst), "v"(hv32) : "memory");
        }
        float c_reg = c0[(size_t)layer * BATCH * HID + (size_t)(g * GB + b_l) * HID + hc0 + c_l];

        bar_signal(gflags, wl, ++fid);
        bar_poll(gflags, fid);

        const u16* Xsrc = (layer == 0) ? Xbf : Y0bf;
        const u16* WxB  = WxBf + ((size_t)layer * G4 + (size_t)wv * 1024 + hc0 + fr) * HID + fg * 8;
        const size_t xrow = (size_t)(g * GB + fr) * HID + fg * 8;

        int cur = 0;
        float h_out = 0.f;
        f32x4 accx = xgemm(Xsrc + xrow, WxB);   // prologue t=0

        for (int t = 0; t < SEQ; ++t) {
            // ---- stage h(t) -> LDS fragment order (sc-loads from L3) ----
            {
                const u16* hsrc = hbuf + ((size_t)(g * 2 + cur) * GB + sr) * HID + scb * 8;
                uint4 h0v, h1v, h2v, h3v, h4v, h5v, h6v, h7v;
                LDH(h0v,    "0"); LDH(h1v,  "256"); LDH(h2v,  "512"); LDH(h3v,  "768");
                LDH(h4v, "1024"); LDH(h5v, "1280"); LDH(h6v, "1536"); LDH(h7v, "1792");
                asm volatile("s_waitcnt vmcnt(0)" ::: "memory");
                __builtin_amdgcn_sched_barrier(0);
                const int base = (scb >> 2) * 512 + ((scb & 3) * 16 + sr) * 8;  // elems
                *(uint4*)&hstage[base         ] = h0v;
                *(uint4*)&hstage[base + 1*2048] = h1v;
                *(uint4*)&hstage[base + 2*2048] = h2v;
                *(uint4*)&hstage[base + 3*2048] = h3v;
                *(uint4*)&hstage[base + 4*2048] = h4v;
                *(uint4*)&hstage[base + 5*2048] = h5v;
                *(uint4*)&hstage[base + 6*2048] = h6v;
                *(uint4*)&hstage[base + 7*2048] = h7v;
            }
            __syncthreads();

            // ---- h GEMM from LDS (2 independent chains) ----
            f32x4 acc0 = accx;
            f32x4 acc1 = {0.f, 0.f, 0.f, 0.f};
            {
                const u16* Ah = &hstage[lane * 8];
                const u16* Bh = &WhL[wv][lane * 8];
                #pragma unroll
                for (int ks = 0; ks < 32; ks += 2) {
                    bf16x8 a0 = *(const bf16x8*)(Ah + ks * 512);
                    bf16x8 b0 = *(const bf16x8*)(Bh + ks * 512);
                    acc0 = __builtin_amdgcn_mfma_f32_16x16x32_bf16(a0, b0, acc0, 0, 0, 0);
                    bf16x8 a1 = *(const bf16x8*)(Ah + (ks + 1) * 512);
                    bf16x8 b1 = *(const bf16x8*)(Bh + (ks + 1) * 512);
                    acc1 = __builtin_amdgcn_mfma_f32_16x16x32_bf16(a1, b1, acc1, 0, 0, 0);
                }
            }
            __syncthreads();   // hstage fully consumed; gbuf region reusable

            // ---- gates -> gbuf (cross-wave exchange) ----
            #pragma unroll
            for (int i = 0; i < 4; ++i)
                gbuf[(wv * 16 + fg * 4 + i) * 17 + fr] = acc0[i] + acc1[i] + bias_v;
            __syncthreads();

            // ---- cell update: thread (b_l, c_l) ----
            float gi = gbuf[(0 * 16 + b_l) * 17 + c_l];
            float gf = gbuf[(1 * 16 + b_l) * 17 + c_l];
            float gg = gbuf[(2 * 16 + b_l) * 17 + c_l];
            float go = gbuf[(3 * 16 + b_l) * 17 + c_l];
            c_reg = sigmoid_f(gf) * c_reg + sigmoid_f(gi) * tanh_f(gg);
            h_out = sigmoid_f(go) * tanh_f(c_reg);

            u16 hb = f2bf(h_out);
            {
                u16* hdst = hbuf + ((size_t)(g * 2 + (cur ^ 1)) * GB + b_l) * HID + hc0 + c_l;
                unsigned int hv32 = hb;
                asm volatile("global_store_short %0, %1, off sc0 sc1" :: "v"(hdst), "v"(hv32) : "memory");
            }
            if (layer == 0) {
                u16* ydst = Y0bf + ((size_t)t * BATCH + g * GB + b_l) * HID + hc0 + c_l;
                unsigned int hv32 = hb;
                asm volatile("global_store_short %0, %1, off sc0 sc1" :: "v"(ydst), "v"(hv32) : "memory");
            } else {
                ys[((size_t)t * BATCH + g * GB + b_l) * HID + hc0 + c_l] = h_out;
            }

            // ---- pipelined group barrier with x-prefetch overlap ----
            ++fid;
            bar_signal(gflags, wl, fid);
            int tn = (t + 1) & 255;
            f32x4 accn = xgemm(Xsrc + (size_t)tn * BATCH * HID + xrow, WxB);
            bar_poll(gflags, fid);
            accx = accn;
            cur ^= 1;
        }

        hT[(size_t)layer * BATCH * HID + (size_t)(g * GB + b_l) * HID + hc0 + c_l] = h_out;
        cT[(size_t)layer * BATCH * HID + (size_t)(g * GB + b_l) * HID + hc0 + c_l] = c_reg;

        bar_signal(gflags, wl, ++fid);
        bar_poll(gflags, fid);
        if (layer == 0) {             // robustness: drop any stale L2 lines before plain Y0 reads
            if (tid == 0) __threadfence();
            __syncthreads();
        }
    }
}

extern "C" void kernel_launch(void* const* d_in, const int* in_sizes, int n_in,
                              void* d_out, int out_size, void* d_ws, size_t ws_size,
                              hipStream_t stream) {
    const float* x  = (const float*)d_in[0];
    const float* h0 = (const float*)d_in[1];
    const float* c0 = (const float*)d_in[2];
    const float* Wx = (const float*)d_in[3];
    const float* bx = (const float*)d_in[4];
    const float* Wh = (const float*)d_in[5];
    const float* bh = (const float*)d_in[6];
    float* out = (float*)d_out;

    u16* Xbf  = (u16*)d_ws;                                    // 16.78M elems
    u16* Y0bf = Xbf  + (size_t)SEQ * BATCH * HID;              // 16.78M elems
    u16* WxBf = Y0bf + (size_t)SEQ * BATCH * HID;              // 8.39M elems
    u16* hbuf = WxBf + (size_t)2 * G4 * HID;                   // 131072 elems
    int* flags = (int*)(hbuf + (size_t)4 * 2 * GB * HID);

    prep_kernel<<<dim3(1024), dim3(256), 0, stream>>>(x, Xbf, Wx, WxBf, flags);

    void* args[] = {(void*)&Xbf, (void*)&Y0bf, (void*)&WxBf, (void*)&hbuf, (void*)&flags,
                    (void*)&h0, (void*)&c0, (void*)&Wh, (void*)&bx, (void*)&bh, (void*)&out};
    hipLaunchCooperativeKernel((void*)lstm_coop, dim3(NWG), dim3(256), args, 0, stream);
}